// Round 6
// baseline (252.095 us; speedup 1.0000x reference)
//
#include <hip/hip_runtime.h>
#include <hip/hip_cooperative_groups.h>

namespace cg = cooperative_groups;

// Problem constants
//   m1:(1,1,4096,64) m2:(1,1,6144,64) m3:(1,1,8192,64) m4:(1,1,4096,64) fp32
//   WQ_w:(3,64,64) WQ_b:(3,64) WK_w:(4,3,64,64) WK_b:(4,3,64)
//   out:(1,4096,32) fp32
//
// Workspace layout (float units):
//   Qb   bf16 [4096][64]                 @ 0          (131072 fl)
//   Kb   bf16 per module [T_m][64]       @ 131072     (720896 fl)
//   SP   fp32 356 slots x 2048 (d*32+e)  @ 851968     (729088 fl)
//   TD   fp32 dense t2 per module        @ 1581056    (22528 fl)
//   CTAB int[4][64][2] tile c-bounds     @ 1603584    (512)

#define QB_OFF   0
#define KB_OFF   131072
#define SP_OFF   851968
#define TD_OFF   1581056
#define C_OFF    1603584

typedef __attribute__((ext_vector_type(8))) short short8;    // bf16 frag (4 VGPR)
typedef __attribute__((ext_vector_type(4))) float floatx4;   // MFMA C/D

__device__ __forceinline__ unsigned short f2bf(float f) {
    union { float f; unsigned u; } v; v.f = f;
    unsigned r = v.u + 0x7fff + ((v.u >> 16) & 1);   // RNE
    return (unsigned short)(r >> 16);
}

#define MFMA16(a,b,c) __builtin_amdgcn_mfma_f32_16x16x32_bf16((a),(b),(c),0,0,0)

struct P1 {
    unsigned short H[128*72];    // activations [row][col]
    unsigned short KT[64*136];   // K^T [d][j], j=0..127
    unsigned short VT[32*136];   // V^T [e][j], j=0..127
};
struct P3 {
    unsigned short qs[64*72];    // Q  [i][d]
    unsigned short kc[64*72];    // K  [j][d] chunk
    unsigned short vt[32*72];    // V^T [e][j] chunk
    unsigned short st[32*72];    // S^T [e][d]
    unsigned short ps[64*72];    // masked P [i][j]
    float tq[64];
    float tcs[64];
};
union __align__(16) SMem { P1 p1; P3 p3; };

// ---------------------------------------------------------------------------
// Single cooperative kernel: phase1 (MLP+chunk sums+out-zero) -> grid sync ->
// phase2 (prefix scan + ctab) -> grid sync -> phase3 (tiled masked query).
__global__ __launch_bounds__(256) void k_all(
    const float* __restrict__ x0, const float* __restrict__ x1,
    const float* __restrict__ x2, const float* __restrict__ x3,
    const float* __restrict__ wq_w, const float* __restrict__ wq_b,
    const float* __restrict__ wk_w, const float* __restrict__ wk_b,
    float* __restrict__ ws, float* __restrict__ out)
{
    __shared__ SMem sm;
    cg::grid_group grid = cg::this_grid();

    const int tid = threadIdx.x;
    const int bid = blockIdx.x;
    const float* Xs[4] = {x0, x1, x2, x3};
    const int rowoff[4] = {0, 4096, 10240, 18432};
    const int spoff[4]  = {0, 65, 162, 291};

    const int w    = tid >> 6;
    const int lane = tid & 63;
    const int lm   = lane & 15;
    const int q    = lane >> 4;
    const int col  = w*16 + lm;          // output column this lane owns

    // ======================= PHASE 1 =======================
    if (bid >= 208) {
        // idle blocks zero d_out (replaces hipMemsetAsync)
        float4 z = make_float4(0.f, 0.f, 0.f, 0.f);
        for (int i = (bid-208)*256 + tid; i < 32768; i += 12288)
            ((float4*)out)[i] = z;
    } else {
        int task, rb;
        if (bid < 32)       { task = 0; rb = bid; }
        else if (bid < 64)  { task = 1; rb = bid - 32; }
        else if (bid < 112) { task = 2; rb = bid - 64; }
        else if (bid < 176) { task = 3; rb = bid - 112; }
        else                { task = 4; rb = bid - 176; }

        const float* X; const float* W; const float* Bv; int mm = -1;
        if (task == 0) { X = x0; W = wq_w; Bv = wq_b; }
        else {
            mm = task - 1;
            X = Xs[mm]; W = wk_w + mm*3*64*64; Bv = wk_b + mm*3*64;
        }
        const int row0 = rb * 128;

        // W B-frags + bias straight from global into registers (L2-hot)
        short8 wb[3][2]; float bias[3];
        #pragma unroll
        for (int l = 0; l < 3; ++l) {
            bias[l] = Bv[l*64 + col];
            #pragma unroll
            for (int ks = 0; ks < 2; ++ks) {
                short8 b;
                #pragma unroll
                for (int j = 0; j < 8; ++j)
                    b[j] = (short)f2bf(W[l*4096 + (ks*32 + q*8 + j)*64 + col]);
                wb[l][ks] = b;
            }
        }

        // stage X tile -> H bf16 [row][col]
        {
            const float4* X4 = (const float4*)(X + (size_t)row0*64);
            #pragma unroll
            for (int k = 0; k < 8; ++k) {
                int idx = k*256 + tid;
                float4 v = X4[idx];
                int rr = idx >> 4, c4 = (idx & 15) * 4;
                ushort4 h;
                h.x = f2bf(v.x); h.y = f2bf(v.y); h.z = f2bf(v.z); h.w = f2bf(v.w);
                *(ushort4*)&sm.p1.H[rr*72 + c4] = h;
            }
        }
        // dense timestamps (fp32, never through bf16)
        if (task > 0 && tid < 128)
            ws[TD_OFF + rowoff[mm] + row0 + tid] = X[(size_t)(row0 + tid)*64 + 63];
        __syncthreads();

        // 3 layers, single H buffer: read frags -> sync -> MFMA+write -> sync
        #pragma unroll 1
        for (int l = 0; l < 3; ++l) {
            short8 a[8][2];
            #pragma unroll
            for (int mt = 0; mt < 8; ++mt) {
                a[mt][0] = *(const short8*)&sm.p1.H[(mt*16+lm)*72 + q*8];
                a[mt][1] = *(const short8*)&sm.p1.H[(mt*16+lm)*72 + 32 + q*8];
            }
            __syncthreads();
            #pragma unroll
            for (int mt = 0; mt < 8; ++mt) {
                floatx4 acc = {bias[l], bias[l], bias[l], bias[l]};
                acc = MFMA16(a[mt][0], wb[l][0], acc);
                acc = MFMA16(a[mt][1], wb[l][1], acc);
                int r0 = mt*16 + q*4;
                #pragma unroll
                for (int r = 0; r < 4; ++r) {
                    float f = acc[r];
                    if (l < 2) f = fmaxf(f, 0.0f);
                    unsigned short hb = f2bf(f);
                    sm.p1.H[(r0+r)*72 + col] = hb;
                    if (l == 2 && task > 0) sm.p1.KT[col*136 + r0 + r] = hb;
                }
            }
            __syncthreads();
        }

        // coalesced bf16 global store of final activations (Q or K)
        {
            unsigned short* dst = (task == 0)
                ? (unsigned short*)(ws + QB_OFF)
                : (unsigned short*)(ws + KB_OFF) + (size_t)rowoff[mm]*64;
            #pragma unroll
            for (int k = 0; k < 8; ++k) {
                int idx = k*256 + tid;
                int rr = idx >> 4, c4 = (idx & 15) * 4;
                *(ushort4*)&dst[(size_t)(row0 + rr)*64 + c4] =
                    *(ushort4*)&sm.p1.H[rr*72 + c4];
            }
        }

        if (task > 0) {
            // stage V^T (X cols 0..31)
            #pragma unroll
            for (int k = 0; k < 4; ++k) {
                int idx = k*256 + tid;
                int j = idx >> 3, e4 = (idx & 7) * 4;
                float4 v = *(const float4*)&X[(size_t)(row0 + j)*64 + e4];
                sm.p1.VT[(e4+0)*136 + j] = f2bf(v.x);
                sm.p1.VT[(e4+1)*136 + j] = f2bf(v.y);
                sm.p1.VT[(e4+2)*136 + j] = f2bf(v.z);
                sm.p1.VT[(e4+3)*136 + j] = f2bf(v.w);
            }
            float* spbase = ws + SP_OFF + (size_t)spoff[mm]*2048;
            if (rb == 0)
                for (int idx = tid; idx < 2048; idx += 256) spbase[idx] = 0.0f;
            __syncthreads();

            // chunk sums S_c[d][e] = sum_j K[j][d] V[j][e]
            #pragma unroll 1
            for (int cc = 0; cc < 2; ++cc) {
                float* slot = spbase + (size_t)(2*rb + cc + 1) * 2048;
                #pragma unroll
                for (int nt = 0; nt < 2; ++nt) {
                    floatx4 acc = {0.f, 0.f, 0.f, 0.f};
                    #pragma unroll
                    for (int ks = 0; ks < 2; ++ks) {
                        short8 aa = *(const short8*)&sm.p1.KT[col*136 + cc*64 + ks*32 + q*8];
                        short8 bb = *(const short8*)&sm.p1.VT[(nt*16+lm)*136 + cc*64 + ks*32 + q*8];
                        acc = MFMA16(aa, bb, acc);
                    }
                    #pragma unroll
                    for (int r = 0; r < 4; ++r)
                        slot[(w*16 + q*4 + r)*32 + nt*16 + lm] = acc[r];
                }
            }
        }
    }

    __threadfence();
    grid.sync();

    // ======================= PHASE 2 =======================
    if (bid < 32) {
        const int nslots[4] = {65, 97, 129, 65};
        int chain = bid*256 + tid;              // 8192 chains
        int m = chain >> 11, entry = chain & 2047;
        float* p = ws + SP_OFF + (size_t)spoff[m]*2048 + entry;
        const int n = nslots[m];
        float s = 0.0f;
        #pragma unroll 8
        for (int k = 0; k < n; ++k) {
            float v = p[(size_t)k*2048];
            s += v;
            p[(size_t)k*2048] = s;
        }
    } else if (bid < 34) {
        const int Tm[4] = {4096, 6144, 8192, 4096};
        const float* td = ws + TD_OFF;
        int* ctab = (int*)(ws + C_OFF);
        int g = (bid - 32)*256 + tid;           // 0..511
        int m = g >> 7, tile = (g >> 1) & 63, bound = g & 1;
        float t = td[tile*64 + (bound ? 63 : 0)];
        const float* t2 = td + rowoff[m];
        int lo = 0, hi = Tm[m];
        while (lo < hi) {
            int mid = (lo + hi) >> 1;
            if (t2[mid] <= t) lo = mid + 1; else hi = mid;
        }
        ctab[g] = lo;
    }

    __threadfence();
    grid.sync();

    // ======================= PHASE 3 =======================
    {
        const int m    = bid & 3;
        const int tile = bid >> 2;
        const int i0   = tile * 64;
        const float* X = Xs[m];

        const int* ctab = (const int*)(ws + C_OFF);
        const int c_lo = ctab[m*128 + tile*2 + 0];
        const int c_hi = ctab[m*128 + tile*2 + 1];
        const int B0   = c_lo >> 6;
        const int Bhi  = (c_hi + 63) >> 6;

        const unsigned short* Qg = (const unsigned short*)(ws + QB_OFF);
        const unsigned short* Kg = (const unsigned short*)(ws + KB_OFF) + (size_t)rowoff[m]*64;
        const float* td = ws + TD_OFF;
        const float* sp = ws + SP_OFF + (size_t)(spoff[m] + B0)*2048;

        // stage Q, S^T, t1
        #pragma unroll
        for (int k = 0; k < 4; ++k) {
            int idx = k*256 + tid;
            int rr = idx >> 4, c4 = (idx & 15) * 4;
            *(ushort4*)&sm.p3.qs[rr*72 + c4] =
                *(const ushort4*)&Qg[(size_t)(i0 + rr)*64 + c4];
        }
        #pragma unroll
        for (int k = 0; k < 8; ++k) {
            int idx = k*256 + tid;
            int d = idx >> 5, e = idx & 31;
            sm.p3.st[e*72 + d] = f2bf(sp[idx]);
        }
        if (tid < 64) sm.p3.tq[tid] = td[i0 + tid];
        __syncthreads();

        float t1v[16];
        #pragma unroll
        for (int mt = 0; mt < 4; ++mt)
            #pragma unroll
            for (int r = 0; r < 4; ++r)
                t1v[mt*4 + r] = sm.p3.tq[mt*16 + q*4 + r];

        short8 qa[4][2];
        #pragma unroll
        for (int mt = 0; mt < 4; ++mt) {
            qa[mt][0] = *(const short8*)&sm.p3.qs[(mt*16+lm)*72 + q*8];
            qa[mt][1] = *(const short8*)&sm.p3.qs[(mt*16+lm)*72 + 32 + q*8];
        }

        // state: O = Q · S
        floatx4 accO[2];
        #pragma unroll
        for (int nt = 0; nt < 2; ++nt) {
            floatx4 acc = {0.f, 0.f, 0.f, 0.f};
            #pragma unroll
            for (int ks = 0; ks < 2; ++ks) {
                short8 b = *(const short8*)&sm.p3.st[(nt*16+lm)*72 + ks*32 + q*8];
                acc = MFMA16(qa[w][ks], b, acc);
            }
            accO[nt] = acc;
        }

        // boundary chunks with explicit fp32 time mask
        #pragma unroll 1
        for (int B = B0; B < Bhi; ++B) {
            __syncthreads();
            #pragma unroll
            for (int k = 0; k < 4; ++k) {
                int idx = k*256 + tid;
                int j = idx >> 4, c4 = (idx & 15) * 4;
                *(ushort4*)&sm.p3.kc[j*72 + c4] =
                    *(const ushort4*)&Kg[(size_t)(B*64 + j)*64 + c4];
            }
            #pragma unroll
            for (int k = 0; k < 2; ++k) {
                int idx = k*256 + tid;
                int j = idx >> 3, e4 = (idx & 7) * 4;
                float4 v = *(const float4*)&X[(size_t)(B*64 + j)*64 + e4];
                sm.p3.vt[(e4+0)*72 + j] = f2bf(v.x);
                sm.p3.vt[(e4+1)*72 + j] = f2bf(v.y);
                sm.p3.vt[(e4+2)*72 + j] = f2bf(v.z);
                sm.p3.vt[(e4+3)*72 + j] = f2bf(v.w);
            }
            if (tid < 64) sm.p3.tcs[tid] = td[rowoff[m] + B*64 + tid];
            __syncthreads();

            // scores + mask -> ps
            {
                short8 bk0 = *(const short8*)&sm.p3.kc[(w*16+lm)*72 + q*8];
                short8 bk1 = *(const short8*)&sm.p3.kc[(w*16+lm)*72 + 32 + q*8];
                float t2j = sm.p3.tcs[w*16 + lm];
                #pragma unroll
                for (int mt = 0; mt < 4; ++mt) {
                    floatx4 f = {0.f, 0.f, 0.f, 0.f};
                    f = MFMA16(qa[mt][0], bk0, f);
                    f = MFMA16(qa[mt][1], bk1, f);
                    #pragma unroll
                    for (int r = 0; r < 4; ++r) {
                        float p = (t2j <= t1v[mt*4 + r]) ? f[r] : 0.0f;
                        sm.p3.ps[(mt*16 + q*4 + r)*72 + w*16 + lm] = f2bf(p);
                    }
                }
            }
            __syncthreads();

            // O += P·V
            {
                short8 pa0 = *(const short8*)&sm.p3.ps[(w*16+lm)*72 + q*8];
                short8 pa1 = *(const short8*)&sm.p3.ps[(w*16+lm)*72 + 32 + q*8];
                #pragma unroll
                for (int nt = 0; nt < 2; ++nt) {
                    short8 bv0 = *(const short8*)&sm.p3.vt[(nt*16+lm)*72 + q*8];
                    short8 bv1 = *(const short8*)&sm.p3.vt[(nt*16+lm)*72 + 32 + q*8];
                    accO[nt] = MFMA16(pa0, bv0, accO[nt]);
                    accO[nt] = MFMA16(pa1, bv1, accO[nt]);
                }
            }
        }

        // combine modules (d_out zeroed in phase 1)
        #pragma unroll
        for (int nt = 0; nt < 2; ++nt)
            #pragma unroll
            for (int r = 0; r < 4; ++r) {
                int i = w*16 + q*4 + r;
                int e = nt*16 + lm;
                atomicAdd(&out[(size_t)(i0 + i)*32 + e], accO[nt][r]);
            }
    }
}

extern "C" void kernel_launch(void* const* d_in, const int* in_sizes, int n_in,
                              void* d_out, int out_size, void* d_ws, size_t ws_size,
                              hipStream_t stream) {
    const float* x0   = (const float*)d_in[0];
    const float* x1   = (const float*)d_in[1];
    const float* x2   = (const float*)d_in[2];
    const float* x3   = (const float*)d_in[3];
    const float* wq_w = (const float*)d_in[4];
    const float* wq_b = (const float*)d_in[5];
    const float* wk_w = (const float*)d_in[6];
    const float* wk_b = (const float*)d_in[7];
    float* ws  = (float*)d_ws;
    float* out = (float*)d_out;

    void* args[] = {(void*)&x0, (void*)&x1, (void*)&x2, (void*)&x3,
                    (void*)&wq_w, (void*)&wq_b, (void*)&wk_w, (void*)&wk_b,
                    (void*)&ws, (void*)&out};
    hipLaunchCooperativeKernel((const void*)k_all, dim3(256), dim3(256),
                               args, 0, stream);
}

// Round 7
// 140.719 us; speedup vs baseline: 1.7915x; 1.7915x over previous
//
#include <hip/hip_runtime.h>

// Problem constants
//   m1:(1,1,4096,64) m2:(1,1,6144,64) m3:(1,1,8192,64) m4:(1,1,4096,64) fp32
//   WQ_w:(3,64,64) WQ_b:(3,64) WK_w:(4,3,64,64) WK_b:(4,3,64)
//   out:(1,4096,32) fp32
//
// Workspace layout (float units):
//   Qb   bf16 [4096][64]                 @ 0          (131072 fl)
//   Kb   bf16 per module [T_m][64]       @ 131072     (720896 fl)
//   SP   fp32 356 slots x 2048 (d*32+e)  @ 851968     (729088 fl)
//   TD   fp32 dense t2 per module        @ 1581056    (22528 fl)
//   CTAB int[4][64][2] tile c-bounds     @ 1603584    (512)

#define QB_OFF   0
#define KB_OFF   131072
#define SP_OFF   851968
#define TD_OFF   1581056
#define C_OFF    1603584

typedef __attribute__((ext_vector_type(8))) short short8;    // bf16 frag (4 VGPR)
typedef __attribute__((ext_vector_type(4))) float floatx4;   // MFMA C/D

__device__ __forceinline__ unsigned short f2bf(float f) {
    union { float f; unsigned u; } v; v.f = f;
    unsigned r = v.u + 0x7fff + ((v.u >> 16) & 1);   // RNE
    return (unsigned short)(r >> 16);
}

#define MFMA16(a,b,c) __builtin_amdgcn_mfma_f32_16x16x32_bf16((a),(b),(c),0,0,0)

// ---------------------------------------------------------------------------
// Fused MLP + chunk sums. 64-row tiles -> 416 blocks:
//   Q: bid 0..63 | K m0: 64..127 | m1: 128..223 | m2: 224..351 | m3: 352..415
// W held entirely in registers (24 VGPRs of B-frags + 3 bias). One barrier
// per layer (H0/H1 double buffer). Q blocks also zero d_out (replaces memset).
// LDS ~31.5 KB -> ~4 blocks/CU.
__global__ __launch_bounds__(256) void k_fused(
    const float* __restrict__ x0, const float* __restrict__ x1,
    const float* __restrict__ x2, const float* __restrict__ x3,
    const float* __restrict__ wq_w, const float* __restrict__ wq_b,
    const float* __restrict__ wk_w, const float* __restrict__ wk_b,
    float* __restrict__ ws, float* __restrict__ out)
{
    __shared__ unsigned short H0[64*72];   // activations ping
    __shared__ unsigned short H1[64*72];   // activations pong
    __shared__ unsigned short KT[64*72];   // K^T [d][j], one 64-chunk
    __shared__ unsigned short VT[32*72];   // V^T [e][j]

    const int tid = threadIdx.x;
    const int bid = blockIdx.x;

    int task, rb;
    if (bid < 64)       { task = 0; rb = bid; }
    else if (bid < 128) { task = 1; rb = bid - 64; }
    else if (bid < 224) { task = 2; rb = bid - 128; }
    else if (bid < 352) { task = 3; rb = bid - 224; }
    else                { task = 4; rb = bid - 352; }

    const float* Xs[4] = {x0, x1, x2, x3};
    const int rowoff[4] = {0, 4096, 10240, 18432};
    const int spoff[4]  = {0, 65, 162, 291};

    const float* X; const float* W; const float* Bv; int mm = -1;
    if (task == 0) { X = x0; W = wq_w; Bv = wq_b; }
    else {
        mm = task - 1;
        X = Xs[mm]; W = wk_w + mm*3*64*64; Bv = wk_b + mm*3*64;
    }

    const int w    = tid >> 6;
    const int lane = tid & 63;
    const int lm   = lane & 15;
    const int q    = lane >> 4;
    const int col  = w*16 + lm;          // output column this lane owns

    // d_out zeroing by Q blocks (two dispatch boundaries before k_query)
    if (task == 0) {
        float4 z = make_float4(0.f, 0.f, 0.f, 0.f);
        ((float4*)out)[bid*512 + tid]       = z;
        ((float4*)out)[bid*512 + 256 + tid] = z;
    }

    // W B-frags + bias straight from global into registers (L2-hot)
    short8 wb[3][2]; float bias[3];
    #pragma unroll
    for (int l = 0; l < 3; ++l) {
        bias[l] = Bv[l*64 + col];
        #pragma unroll
        for (int ks = 0; ks < 2; ++ks) {
            short8 b;
            #pragma unroll
            for (int j = 0; j < 8; ++j)
                b[j] = (short)f2bf(W[l*4096 + (ks*32 + q*8 + j)*64 + col]);
            wb[l][ks] = b;
        }
    }

    const int row0 = rb * 64;
    // stage X tile -> H0 bf16 [row][col]
    {
        const float4* X4 = (const float4*)(X + (size_t)row0*64);
        #pragma unroll
        for (int k = 0; k < 4; ++k) {
            int idx = k*256 + tid;            // 0..1023 float4s
            float4 v = X4[idx];
            int rr = idx >> 4, c4 = (idx & 15) * 4;
            ushort4 h;
            h.x = f2bf(v.x); h.y = f2bf(v.y); h.z = f2bf(v.z); h.w = f2bf(v.w);
            *(ushort4*)&H0[rr*72 + c4] = h;
        }
    }
    // dense timestamps (fp32, never through bf16)
    if (task > 0 && tid < 64)
        ws[TD_OFF + rowoff[mm] + row0 + tid] = X[(size_t)(row0 + tid)*64 + 63];
    __syncthreads();

    // 3 MFMA layers, one barrier each (double buffer)
    #pragma unroll 1
    for (int l = 0; l < 3; ++l) {
        const unsigned short* Hin  = (l & 1) ? H1 : H0;
        unsigned short*       Hout = (l & 1) ? H0 : H1;
        #pragma unroll
        for (int mt = 0; mt < 4; ++mt) {
            short8 a0 = *(const short8*)&Hin[(mt*16+lm)*72 + q*8];
            short8 a1 = *(const short8*)&Hin[(mt*16+lm)*72 + 32 + q*8];
            floatx4 acc = {bias[l], bias[l], bias[l], bias[l]};
            acc = MFMA16(a0, wb[l][0], acc);
            acc = MFMA16(a1, wb[l][1], acc);
            int r0 = mt*16 + q*4;
            #pragma unroll
            for (int r = 0; r < 4; ++r) {
                float f = acc[r];
                if (l < 2) f = fmaxf(f, 0.0f);
                unsigned short hb = f2bf(f);
                Hout[(r0+r)*72 + col] = hb;
                if (l == 2 && task > 0) KT[col*72 + r0 + r] = hb;
            }
        }
        __syncthreads();
    }

    // coalesced bf16 global store of final activations (in H1)
    {
        unsigned short* dst = (task == 0)
            ? (unsigned short*)(ws + QB_OFF)
            : (unsigned short*)(ws + KB_OFF) + (size_t)rowoff[mm]*64;
        #pragma unroll
        for (int k = 0; k < 4; ++k) {
            int idx = k*256 + tid;            // 0..1023 ushort4s
            int rr = idx >> 4, c4 = (idx & 15) * 4;
            *(ushort4*)&dst[(size_t)(row0 + rr)*64 + c4] = *(ushort4*)&H1[rr*72 + c4];
        }
    }
    if (task == 0) return;

    // stage V^T (X cols 0..31) + zero module slot 0
    {
        #pragma unroll
        for (int k = 0; k < 2; ++k) {
            int idx = k*256 + tid;            // 0..511 float4s
            int j = idx >> 3, e4 = (idx & 7) * 4;
            float4 v = *(const float4*)&X[(size_t)(row0 + j)*64 + e4];
            VT[(e4+0)*72 + j] = f2bf(v.x);
            VT[(e4+1)*72 + j] = f2bf(v.y);
            VT[(e4+2)*72 + j] = f2bf(v.z);
            VT[(e4+3)*72 + j] = f2bf(v.w);
        }
    }
    float* spbase = ws + SP_OFF + (size_t)spoff[mm]*2048;
    if (rb == 0)
        for (int idx = tid; idx < 2048; idx += 256) spbase[idx] = 0.0f;
    __syncthreads();

    // chunk sum S[d][e] = sum_j K[j][d] V[j][e]; wave w owns d-tile w
    {
        float* slot = spbase + (size_t)(rb + 1) * 2048;
        #pragma unroll
        for (int nt = 0; nt < 2; ++nt) {
            floatx4 acc = {0.f, 0.f, 0.f, 0.f};
            #pragma unroll
            for (int ks = 0; ks < 2; ++ks) {
                short8 aa = *(const short8*)&KT[col*72 + ks*32 + q*8];
                short8 bb = *(const short8*)&VT[(nt*16+lm)*72 + ks*32 + q*8];
                acc = MFMA16(aa, bb, acc);
            }
            #pragma unroll
            for (int r = 0; r < 4; ++r)
                slot[(w*16 + q*4 + r)*32 + nt*16 + lm] = acc[r];
        }
    }
}

// ---------------------------------------------------------------------------
// Blocks 0..127: in-place fp32 scan over SP slots. Blocks 128..129: tile
// c-bounds table (2 binary searches per tile).
__global__ __launch_bounds__(64) void k_prefix(float* __restrict__ ws)
{
    const int nslots[4] = {65, 97, 129, 65};
    const int spoff[4]  = {0, 65, 162, 291};
    const int Tm[4]     = {4096, 6144, 8192, 4096};
    const int rowoff[4] = {0, 4096, 10240, 18432};
    const int bid = blockIdx.x;

    if (bid < 128) {
        const int m = bid >> 5;
        const int entry = (bid & 31)*64 + threadIdx.x;
        float* p = ws + SP_OFF + (size_t)spoff[m]*2048 + entry;
        const int n = nslots[m];
        float s = 0.0f;
        #pragma unroll 8
        for (int k = 0; k < n; ++k) {
            float v = p[(size_t)k*2048];
            s += v;
            p[(size_t)k*2048] = s;
        }
        return;
    }
    const float* td = ws + TD_OFF;
    int* ctab = (int*)(ws + C_OFF);
    #pragma unroll 1
    for (int k = 0; k < 4; ++k) {
        int g = (bid - 128)*256 + k*64 + threadIdx.x;   // 0..511
        int m = g >> 7;
        int tile = (g >> 1) & 63;
        int bound = g & 1;
        float t = td[tile*64 + (bound ? 63 : 0)];
        const float* t2 = td + rowoff[m];
        int lo = 0, hi = Tm[m];
        while (lo < hi) {
            int mid = (lo + hi) >> 1;
            if (t2[mid] <= t) lo = mid + 1; else hi = mid;
        }
        ctab[g] = lo;
    }
}

// ---------------------------------------------------------------------------
// Tiled MFMA query kernel (R5-verified): block = (module m, 64-query tile).
__global__ __launch_bounds__(256) void k_query(
    const float* __restrict__ x0, const float* __restrict__ x1,
    const float* __restrict__ x2, const float* __restrict__ x3,
    float* __restrict__ ws, float* __restrict__ out)
{
    __shared__ unsigned short qs[64*72];   // Q  [i][d]
    __shared__ unsigned short kc[64*72];   // K  [j][d]  (chunk)
    __shared__ unsigned short vt[32*72];   // V^T [e][j] (chunk)
    __shared__ unsigned short st[32*72];   // S^T [e][d]
    __shared__ unsigned short ps[64*72];   // masked P [i][j] (chunk)
    __shared__ float tq[64];               // t1 tile (fp32!)
    __shared__ float tcs[64];              // t2 chunk (fp32!)

    const int tid  = threadIdx.x;
    const int m    = blockIdx.x & 3;
    const int tile = blockIdx.x >> 2;
    const int i0   = tile * 64;

    const float* Xs[4] = {x0, x1, x2, x3};
    const int rowoff[4] = {0, 4096, 10240, 18432};
    const int spoff[4]  = {0, 65, 162, 291};
    const float* X = Xs[m];

    const int* ctab = (const int*)(ws + C_OFF);
    const int c_lo = ctab[m*128 + tile*2 + 0];
    const int c_hi = ctab[m*128 + tile*2 + 1];
    const int B0   = c_lo >> 6;
    const int Bhi  = (c_hi + 63) >> 6;

    const unsigned short* Qg = (const unsigned short*)(ws + QB_OFF);
    const unsigned short* Kg = (const unsigned short*)(ws + KB_OFF) + (size_t)rowoff[m]*64;
    const float* td = ws + TD_OFF;
    const float* sp = ws + SP_OFF + (size_t)(spoff[m] + B0)*2048;

    // stage Q (bf16 copy), S^T (fp32->bf16), t1
    #pragma unroll
    for (int k = 0; k < 4; ++k) {
        int idx = k*256 + tid;
        int rr = idx >> 4, c4 = (idx & 15) * 4;
        *(ushort4*)&qs[rr*72 + c4] = *(const ushort4*)&Qg[(size_t)(i0 + rr)*64 + c4];
    }
    #pragma unroll
    for (int k = 0; k < 8; ++k) {
        int idx = k*256 + tid;
        int d = idx >> 5, e = idx & 31;
        st[e*72 + d] = f2bf(sp[idx]);
    }
    if (tid < 64) tq[tid] = td[i0 + tid];
    __syncthreads();

    const int w    = tid >> 6;
    const int lane = tid & 63;
    const int lm   = lane & 15;
    const int q    = lane >> 4;

    float t1v[16];
    #pragma unroll
    for (int mt = 0; mt < 4; ++mt)
        #pragma unroll
        for (int r = 0; r < 4; ++r)
            t1v[mt*4 + r] = tq[mt*16 + q*4 + r];

    short8 qa[4][2];
    #pragma unroll
    for (int mt = 0; mt < 4; ++mt) {
        qa[mt][0] = *(const short8*)&qs[(mt*16+lm)*72 + q*8];
        qa[mt][1] = *(const short8*)&qs[(mt*16+lm)*72 + 32 + q*8];
    }

    // state: O = Q · S
    floatx4 accO[2];
    #pragma unroll
    for (int nt = 0; nt < 2; ++nt) {
        floatx4 acc = {0.f, 0.f, 0.f, 0.f};
        #pragma unroll
        for (int ks = 0; ks < 2; ++ks) {
            short8 b = *(const short8*)&st[(nt*16+lm)*72 + ks*32 + q*8];
            acc = MFMA16(qa[w][ks], b, acc);
        }
        accO[nt] = acc;
    }

    // boundary chunks with explicit fp32 time mask
    #pragma unroll 1
    for (int B = B0; B < Bhi; ++B) {
        __syncthreads();
        #pragma unroll
        for (int k = 0; k < 4; ++k) {
            int idx = k*256 + tid;
            int j = idx >> 4, c4 = (idx & 15) * 4;
            *(ushort4*)&kc[j*72 + c4] = *(const ushort4*)&Kg[(size_t)(B*64 + j)*64 + c4];
        }
        #pragma unroll
        for (int k = 0; k < 2; ++k) {
            int idx = k*256 + tid;
            int j = idx >> 3, e4 = (idx & 7) * 4;
            float4 v = *(const float4*)&X[(size_t)(B*64 + j)*64 + e4];
            vt[(e4+0)*72 + j] = f2bf(v.x);
            vt[(e4+1)*72 + j] = f2bf(v.y);
            vt[(e4+2)*72 + j] = f2bf(v.z);
            vt[(e4+3)*72 + j] = f2bf(v.w);
        }
        if (tid < 64) tcs[tid] = td[rowoff[m] + B*64 + tid];
        __syncthreads();

        // scores + mask -> ps
        {
            short8 bk0 = *(const short8*)&kc[(w*16+lm)*72 + q*8];
            short8 bk1 = *(const short8*)&kc[(w*16+lm)*72 + 32 + q*8];
            float t2j = tcs[w*16 + lm];
            #pragma unroll
            for (int mt = 0; mt < 4; ++mt) {
                floatx4 f = {0.f, 0.f, 0.f, 0.f};
                f = MFMA16(qa[mt][0], bk0, f);
                f = MFMA16(qa[mt][1], bk1, f);
                #pragma unroll
                for (int r = 0; r < 4; ++r) {
                    float p = (t2j <= t1v[mt*4 + r]) ? f[r] : 0.0f;
                    ps[(mt*16 + q*4 + r)*72 + w*16 + lm] = f2bf(p);
                }
            }
        }
        __syncthreads();

        // O += P·V
        {
            short8 pa0 = *(const short8*)&ps[(w*16+lm)*72 + q*8];
            short8 pa1 = *(const short8*)&ps[(w*16+lm)*72 + 32 + q*8];
            #pragma unroll
            for (int nt = 0; nt < 2; ++nt) {
                short8 bv0 = *(const short8*)&vt[(nt*16+lm)*72 + q*8];
                short8 bv1 = *(const short8*)&vt[(nt*16+lm)*72 + 32 + q*8];
                accO[nt] = MFMA16(pa0, bv0, accO[nt]);
                accO[nt] = MFMA16(pa1, bv1, accO[nt]);
            }
        }
    }

    // combine modules (d_out zeroed by k_fused Q blocks)
    #pragma unroll
    for (int nt = 0; nt < 2; ++nt)
        #pragma unroll
        for (int r = 0; r < 4; ++r) {
            int i = w*16 + q*4 + r;
            int e = nt*16 + lm;
            atomicAdd(&out[(size_t)(i0 + i)*32 + e], accO[nt][r]);
        }
}

extern "C" void kernel_launch(void* const* d_in, const int* in_sizes, int n_in,
                              void* d_out, int out_size, void* d_ws, size_t ws_size,
                              hipStream_t stream) {
    const float* x0   = (const float*)d_in[0];
    const float* x1   = (const float*)d_in[1];
    const float* x2   = (const float*)d_in[2];
    const float* x3   = (const float*)d_in[3];
    const float* wq_w = (const float*)d_in[4];
    const float* wq_b = (const float*)d_in[5];
    const float* wk_w = (const float*)d_in[6];
    const float* wk_b = (const float*)d_in[7];
    float* ws  = (float*)d_ws;
    float* out = (float*)d_out;

    hipLaunchKernelGGL(k_fused,  dim3(416), dim3(256), 0, stream,
                       x0, x1, x2, x3, wq_w, wq_b, wk_w, wk_b, ws, out);
    hipLaunchKernelGGL(k_prefix, dim3(130), dim3(64),  0, stream, ws);
    hipLaunchKernelGGL(k_query,  dim3(256), dim3(256), 0, stream,
                       x0, x1, x2, x3, ws, out);
}

// Round 8
// 112.531 us; speedup vs baseline: 2.2402x; 1.2505x over previous
//
#include <hip/hip_runtime.h>

// Problem constants
//   m1:(1,1,4096,64) m2:(1,1,6144,64) m3:(1,1,8192,64) m4:(1,1,4096,64) fp32
//   WQ_w:(3,64,64) WQ_b:(3,64) WK_w:(4,3,64,64) WK_b:(4,3,64)
//   out:(1,4096,32) fp32
//
// Workspace layout (float units):
//   Qb   bf16 [4096][64]                 @ 0          (131072 fl)
//   Kb   bf16 per module [T_m][64]       @ 131072     (720896 fl)
//   SP   fp32 356 slots x 2048 (d*32+e)  @ 851968     (729088 fl)
//   TD   fp32 dense t2 per module        @ 1581056    (22528 fl)
//   CTAB int[4][64][2] tile c-bounds     @ 1603584    (512)

#define QB_OFF   0
#define KB_OFF   131072
#define SP_OFF   851968
#define TD_OFF   1581056
#define C_OFF    1603584

typedef __attribute__((ext_vector_type(8))) short short8;    // bf16 frag (4 VGPR)
typedef __attribute__((ext_vector_type(4))) float floatx4;   // MFMA C/D

__device__ __forceinline__ unsigned short f2bf(float f) {
    union { float f; unsigned u; } v; v.f = f;
    unsigned r = v.u + 0x7fff + ((v.u >> 16) & 1);   // RNE
    return (unsigned short)(r >> 16);
}

#define MFMA16(a,b,c) __builtin_amdgcn_mfma_f32_16x16x32_bf16((a),(b),(c),0,0,0)

// ---------------------------------------------------------------------------
// Fused: 3-layer MLP (bf16 MFMA) + bf16 Q/K global store + chunk K^T·V sums.
// R5-verified version: 128-row tiles, LDS-staged W (coalesced). 208 blocks.
__global__ __launch_bounds__(256) void k_fused(
    const float* __restrict__ x0, const float* __restrict__ x1,
    const float* __restrict__ x2, const float* __restrict__ x3,
    const float* __restrict__ wq_w, const float* __restrict__ wq_b,
    const float* __restrict__ wk_w, const float* __restrict__ wk_b,
    float* __restrict__ ws)
{
    __shared__ unsigned short H0[128*72];   // act buffer A  [row][d]
    __shared__ unsigned short H1[128*72];   // act buffer B  [row][d]
    __shared__ unsigned short Wt[64*72];    // W^T layer     [c][d]
    __shared__ unsigned short KT[64*136];   // K^T           [d][j]  j=0..127
    __shared__ unsigned short VT[32*136];   // V^T           [e][j]  j=0..127

    const int tid = threadIdx.x;
    const int bid = blockIdx.x;

    int task, rb;
    if (bid < 32)       { task = 0; rb = bid; }
    else if (bid < 64)  { task = 1; rb = bid - 32; }
    else if (bid < 112) { task = 2; rb = bid - 64; }
    else if (bid < 176) { task = 3; rb = bid - 112; }
    else                { task = 4; rb = bid - 176; }

    const float* Xs[4] = {x0, x1, x2, x3};
    const int rowoff[4] = {0, 4096, 10240, 18432};
    const int spoff[4]  = {0, 65, 162, 291};

    const float* X; const float* W; const float* Bv;
    int mm = -1;
    if (task == 0) { X = x0; W = wq_w; Bv = wq_b; }
    else {
        mm = task - 1;
        X = Xs[mm]; W = wk_w + mm*3*64*64; Bv = wk_b + mm*3*64;
    }

    const int row0 = rb * 128;

    // stage X tile -> H0 (bf16 [row][d])
    {
        const float4* X4 = (const float4*)(X + (size_t)row0*64);
        #pragma unroll
        for (int k = 0; k < 8; ++k) {
            int idx = k*256 + tid;            // 0..2047 float4s
            float4 v = X4[idx];
            int rr = idx >> 4, c4 = (idx & 15) * 4;
            ushort4 h;
            h.x = f2bf(v.x); h.y = f2bf(v.y); h.z = f2bf(v.z); h.w = f2bf(v.w);
            *(ushort4*)&H0[rr*72 + c4] = h;
        }
    }
    // dense timestamps straight from global fp32 (must NOT go through bf16)
    if (task > 0 && tid < 128)
        ws[TD_OFF + rowoff[mm] + row0 + tid] = X[(size_t)(row0 + tid)*64 + 63];

    const int w    = tid >> 6;      // wave id = n-tile
    const int lane = tid & 63;
    const int lm   = lane & 15;
    const int q    = lane >> 4;

    #pragma unroll 1
    for (int l = 0; l < 3; ++l) {
        __syncthreads();            // prior-layer frag reads / X stage done
        // stage W^T for this layer (coalesced)
        {
            const float4* W4 = (const float4*)(W + l*4096);
            #pragma unroll
            for (int k = 0; k < 4; ++k) {
                int idx = k*256 + tid;        // 0..1023
                float4 v = W4[idx];
                int d = idx >> 4, c4 = (idx & 15) * 4;
                Wt[(c4+0)*72 + d] = f2bf(v.x);
                Wt[(c4+1)*72 + d] = f2bf(v.y);
                Wt[(c4+2)*72 + d] = f2bf(v.z);
                Wt[(c4+3)*72 + d] = f2bf(v.w);
            }
        }
        __syncthreads();

        const unsigned short* Hin  = (l & 1) ? H1 : H0;
        unsigned short*       Hout = (l & 1) ? H0 : H1;
        float bias = Bv[l*64 + w*16 + lm];
        short8 b0 = *(const short8*)&Wt[(w*16+lm)*72 + q*8];
        short8 b1 = *(const short8*)&Wt[(w*16+lm)*72 + 32 + q*8];
        #pragma unroll
        for (int mt = 0; mt < 8; ++mt) {
            floatx4 acc = {bias, bias, bias, bias};
            short8 a0 = *(const short8*)&Hin[(mt*16+lm)*72 + q*8];
            short8 a1 = *(const short8*)&Hin[(mt*16+lm)*72 + 32 + q*8];
            acc = MFMA16(a0, b0, acc);
            acc = MFMA16(a1, b1, acc);
            int r0 = mt*16 + q*4;
            #pragma unroll
            for (int r = 0; r < 4; ++r) {
                float f = acc[r];
                if (l < 2) f = fmaxf(f, 0.0f);
                unsigned short hb = f2bf(f);
                Hout[(r0+r)*72 + w*16 + lm] = hb;            // [row][col]
                if (l == 2 && task > 0)
                    KT[(w*16+lm)*136 + r0 + r] = hb;         // K^T [d][j]
            }
        }
    }
    __syncthreads();

    // coalesced global bf16 store of the final activations (Q or K)
    {
        unsigned short* dst = (task == 0)
            ? (unsigned short*)(ws + QB_OFF)
            : (unsigned short*)(ws + KB_OFF) + (size_t)rowoff[mm]*64;
        #pragma unroll
        for (int k = 0; k < 8; ++k) {
            int idx = k*256 + tid;            // 0..2047 ushort4s
            int rr = idx >> 4, c4 = (idx & 15) * 4;
            *(ushort4*)&dst[(size_t)(row0 + rr)*64 + c4] = *(ushort4*)&H1[rr*72 + c4];
        }
    }
    if (task == 0) return;

    // stage V^T (X cols 0..31, bf16) + zero module slot 0
    {
        #pragma unroll
        for (int k = 0; k < 4; ++k) {
            int idx = k*256 + tid;            // 0..1023 float4s
            int j = idx >> 3, e4 = (idx & 7) * 4;
            float4 v = *(const float4*)&X[(size_t)(row0 + j)*64 + e4];
            VT[(e4+0)*136 + j] = f2bf(v.x);
            VT[(e4+1)*136 + j] = f2bf(v.y);
            VT[(e4+2)*136 + j] = f2bf(v.z);
            VT[(e4+3)*136 + j] = f2bf(v.w);
        }
    }
    float* spbase = ws + SP_OFF + (size_t)spoff[mm]*2048;
    if (rb == 0)
        for (int idx = tid; idx < 2048; idx += 256) spbase[idx] = 0.0f;
    __syncthreads();

    // chunk sums S_c[d][e] = sum_j K[j][d] V[j][e]  via MFMA (A=K^T, B=V)
    #pragma unroll 1
    for (int c = 0; c < 2; ++c) {
        float* slot = spbase + (size_t)(2*rb + c + 1) * 2048;
        #pragma unroll
        for (int nt = 0; nt < 2; ++nt) {
            floatx4 acc = {0.f, 0.f, 0.f, 0.f};
            #pragma unroll
            for (int ks = 0; ks < 2; ++ks) {
                short8 a = *(const short8*)&KT[(w*16+lm)*136 + c*64 + ks*32 + q*8];
                short8 b = *(const short8*)&VT[(nt*16+lm)*136 + c*64 + ks*32 + q*8];
                acc = MFMA16(a, b, acc);
            }
            #pragma unroll
            for (int r = 0; r < 4; ++r) {
                int d = w*16 + q*4 + r;
                int e = nt*16 + lm;
                slot[d*32 + e] = acc[r];
            }
        }
    }
}

// ---------------------------------------------------------------------------
// Blocks 0..127: in-place fp32 scan over SP slots. Blocks 128..129: tile
// c-bounds table (2 binary searches per tile).
__global__ __launch_bounds__(64) void k_prefix(float* __restrict__ ws)
{
    const int nslots[4] = {65, 97, 129, 65};
    const int spoff[4]  = {0, 65, 162, 291};
    const int Tm[4]     = {4096, 6144, 8192, 4096};
    const int rowoff[4] = {0, 4096, 10240, 18432};
    const int bid = blockIdx.x;

    if (bid < 128) {
        const int m = bid >> 5;
        const int entry = (bid & 31)*64 + threadIdx.x;
        float* p = ws + SP_OFF + (size_t)spoff[m]*2048 + entry;
        const int n = nslots[m];
        float s = 0.0f;
        #pragma unroll 8
        for (int k = 0; k < n; ++k) {
            float v = p[(size_t)k*2048];
            s += v;
            p[(size_t)k*2048] = s;
        }
        return;
    }
    const float* td = ws + TD_OFF;
    int* ctab = (int*)(ws + C_OFF);
    #pragma unroll 1
    for (int k = 0; k < 4; ++k) {
        int g = (bid - 128)*256 + k*64 + threadIdx.x;   // 0..511
        int m = g >> 7;
        int tile = (g >> 1) & 63;
        int bound = g & 1;
        float t = td[tile*64 + (bound ? 63 : 0)];
        const float* t2 = td + rowoff[m];
        int lo = 0, hi = Tm[m];
        while (lo < hi) {
            int mid = (lo + hi) >> 1;
            if (t2[mid] <= t) lo = mid + 1; else hi = mid;
        }
        ctab[g] = lo;
    }
}

// ---------------------------------------------------------------------------
// Tiled MFMA query kernel, chunk-slot split: 512 blocks =
// (module m, 64-query tile, slot in {0,1}). Slot 0: state + chunks B0,B0+2…;
// slot 1: chunks B0+1,B0+3…. Contributions disjoint; combined via atomicAdd.
__global__ __launch_bounds__(256) void k_query(
    const float* __restrict__ x0, const float* __restrict__ x1,
    const float* __restrict__ x2, const float* __restrict__ x3,
    float* __restrict__ ws, float* __restrict__ out)
{
    __shared__ unsigned short qs[64*72];   // Q  [i][d]
    __shared__ unsigned short kc[64*72];   // K  [j][d]  (chunk)
    __shared__ unsigned short vt[32*72];   // V^T [e][j] (chunk)
    __shared__ unsigned short st[32*72];   // S^T [e][d] (slot 0 only)
    __shared__ unsigned short ps[64*72];   // masked P [i][j] (chunk)
    __shared__ float tq[64];               // t1 tile (fp32!)
    __shared__ float tcs[64];              // t2 chunk (fp32!)

    const int tid  = threadIdx.x;
    const int m    = blockIdx.x & 3;
    const int tile = (blockIdx.x >> 2) & 63;
    const int slot = blockIdx.x >> 8;      // 0 or 1
    const int i0   = tile * 64;

    const float* Xs[4] = {x0, x1, x2, x3};
    const int rowoff[4] = {0, 4096, 10240, 18432};
    const int spoff[4]  = {0, 65, 162, 291};
    const float* X = Xs[m];

    const int* ctab = (const int*)(ws + C_OFF);
    const int c_lo = ctab[m*128 + tile*2 + 0];
    const int c_hi = ctab[m*128 + tile*2 + 1];
    const int B0   = c_lo >> 6;
    const int Bhi  = (c_hi + 63) >> 6;

    // nothing for this slot? (state belongs to slot 0)
    if (slot == 1 && B0 + 1 >= Bhi) return;

    const unsigned short* Qg = (const unsigned short*)(ws + QB_OFF);
    const unsigned short* Kg = (const unsigned short*)(ws + KB_OFF) + (size_t)rowoff[m]*64;
    const float* td = ws + TD_OFF;
    const float* sp = ws + SP_OFF + (size_t)(spoff[m] + B0)*2048;

    // stage Q (bf16 copy), t1; S^T only for slot 0
    #pragma unroll
    for (int k = 0; k < 4; ++k) {
        int idx = k*256 + tid;
        int rr = idx >> 4, c4 = (idx & 15) * 4;
        *(ushort4*)&qs[rr*72 + c4] = *(const ushort4*)&Qg[(size_t)(i0 + rr)*64 + c4];
    }
    if (slot == 0) {
        #pragma unroll
        for (int k = 0; k < 8; ++k) {
            int idx = k*256 + tid;
            int d = idx >> 5, e = idx & 31;
            st[e*72 + d] = f2bf(sp[idx]);
        }
    }
    if (tid < 64) tq[tid] = td[i0 + tid];
    __syncthreads();

    const int w    = tid >> 6;
    const int lane = tid & 63;
    const int lm   = lane & 15;
    const int q    = lane >> 4;

    float t1v[16];
    #pragma unroll
    for (int mt = 0; mt < 4; ++mt)
        #pragma unroll
        for (int r = 0; r < 4; ++r)
            t1v[mt*4 + r] = tq[mt*16 + q*4 + r];

    short8 qa[4][2];
    #pragma unroll
    for (int mt = 0; mt < 4; ++mt) {
        qa[mt][0] = *(const short8*)&qs[(mt*16+lm)*72 + q*8];
        qa[mt][1] = *(const short8*)&qs[(mt*16+lm)*72 + 32 + q*8];
    }

    floatx4 accO[2];
    accO[0] = (floatx4){0.f, 0.f, 0.f, 0.f};
    accO[1] = (floatx4){0.f, 0.f, 0.f, 0.f};

    // state: O = Q · S (slot 0 only)
    if (slot == 0) {
        #pragma unroll
        for (int nt = 0; nt < 2; ++nt) {
            #pragma unroll
            for (int ks = 0; ks < 2; ++ks) {
                short8 b = *(const short8*)&st[(nt*16+lm)*72 + ks*32 + q*8];
                accO[nt] = MFMA16(qa[w][ks], b, accO[nt]);
            }
        }
    }

    // boundary chunks (this slot's parity) with explicit fp32 time mask
    #pragma unroll 1
    for (int B = B0 + slot; B < Bhi; B += 2) {
        __syncthreads();
        #pragma unroll
        for (int k = 0; k < 4; ++k) {
            int idx = k*256 + tid;
            int j = idx >> 4, c4 = (idx & 15) * 4;
            *(ushort4*)&kc[j*72 + c4] = *(const ushort4*)&Kg[(size_t)(B*64 + j)*64 + c4];
        }
        #pragma unroll
        for (int k = 0; k < 2; ++k) {
            int idx = k*256 + tid;
            int j = idx >> 3, e4 = (idx & 7) * 4;
            float4 v = *(const float4*)&X[(size_t)(B*64 + j)*64 + e4];
            vt[(e4+0)*72 + j] = f2bf(v.x);
            vt[(e4+1)*72 + j] = f2bf(v.y);
            vt[(e4+2)*72 + j] = f2bf(v.z);
            vt[(e4+3)*72 + j] = f2bf(v.w);
        }
        if (tid < 64) tcs[tid] = td[rowoff[m] + B*64 + tid];
        __syncthreads();

        // scores + mask -> ps
        {
            short8 bk0 = *(const short8*)&kc[(w*16+lm)*72 + q*8];
            short8 bk1 = *(const short8*)&kc[(w*16+lm)*72 + 32 + q*8];
            float t2j = tcs[w*16 + lm];
            #pragma unroll
            for (int mt = 0; mt < 4; ++mt) {
                floatx4 f = {0.f, 0.f, 0.f, 0.f};
                f = MFMA16(qa[mt][0], bk0, f);
                f = MFMA16(qa[mt][1], bk1, f);
                #pragma unroll
                for (int r = 0; r < 4; ++r) {
                    float p = (t2j <= t1v[mt*4 + r]) ? f[r] : 0.0f;
                    ps[(mt*16 + q*4 + r)*72 + w*16 + lm] = f2bf(p);
                }
            }
        }
        __syncthreads();

        // O += P·V
        {
            short8 pa0 = *(const short8*)&ps[(w*16+lm)*72 + q*8];
            short8 pa1 = *(const short8*)&ps[(w*16+lm)*72 + 32 + q*8];
            #pragma unroll
            for (int nt = 0; nt < 2; ++nt) {
                short8 bv0 = *(const short8*)&vt[(nt*16+lm)*72 + q*8];
                short8 bv1 = *(const short8*)&vt[(nt*16+lm)*72 + 32 + q*8];
                accO[nt] = MFMA16(pa0, bv0, accO[nt]);
                accO[nt] = MFMA16(pa1, bv1, accO[nt]);
            }
        }
    }

    // combine (d_out pre-zeroed by memset)
    #pragma unroll
    for (int nt = 0; nt < 2; ++nt)
        #pragma unroll
        for (int r = 0; r < 4; ++r) {
            int i = w*16 + q*4 + r;
            int e = nt*16 + lm;
            atomicAdd(&out[(size_t)(i0 + i)*32 + e], accO[nt][r]);
        }
}

extern "C" void kernel_launch(void* const* d_in, const int* in_sizes, int n_in,
                              void* d_out, int out_size, void* d_ws, size_t ws_size,
                              hipStream_t stream) {
    const float* x0   = (const float*)d_in[0];
    const float* x1   = (const float*)d_in[1];
    const float* x2   = (const float*)d_in[2];
    const float* x3   = (const float*)d_in[3];
    const float* wq_w = (const float*)d_in[4];
    const float* wq_b = (const float*)d_in[5];
    const float* wk_w = (const float*)d_in[6];
    const float* wk_b = (const float*)d_in[7];
    float* ws  = (float*)d_ws;
    float* out = (float*)d_out;

    hipMemsetAsync(out, 0, (size_t)out_size * sizeof(float), stream);
    hipLaunchKernelGGL(k_fused,  dim3(208), dim3(256), 0, stream,
                       x0, x1, x2, x3, wq_w, wq_b, wk_w, wk_b, ws);
    hipLaunchKernelGGL(k_prefix, dim3(130), dim3(64),  0, stream, ws);
    hipLaunchKernelGGL(k_query,  dim3(512), dim3(256), 0, stream,
                       x0, x1, x2, x3, ws, out);
}

// Round 9
// 106.648 us; speedup vs baseline: 2.3638x; 1.0552x over previous
//
#include <hip/hip_runtime.h>

// Problem constants
//   m1:(1,1,4096,64) m2:(1,1,6144,64) m3:(1,1,8192,64) m4:(1,1,4096,64) fp32
//   WQ_w:(3,64,64) WQ_b:(3,64) WK_w:(4,3,64,64) WK_b:(4,3,64)
//   out:(1,4096,32) fp32
//
// Workspace layout (float units):
//   Qb   bf16 [4096][64]                 @ 0          (131072 fl)
//   Kb   bf16 per module [T_m][64]       @ 131072     (720896 fl)
//   SP   fp32 356 slots x 2048 (d*32+e)  @ 851968     (729088 fl)
//   TD   fp32 dense t2 per module        @ 1581056    (22528 fl)
//   CTAB int[4][64][2] tile c-bounds     @ 1603584    (512)

#define QB_OFF   0
#define KB_OFF   131072
#define SP_OFF   851968
#define TD_OFF   1581056
#define C_OFF    1603584

typedef __attribute__((ext_vector_type(8))) short short8;    // bf16 frag (4 VGPR)
typedef __attribute__((ext_vector_type(4))) float floatx4;   // MFMA C/D

__device__ __forceinline__ unsigned short f2bf(float f) {
    union { float f; unsigned u; } v; v.f = f;
    unsigned r = v.u + 0x7fff + ((v.u >> 16) & 1);   // RNE
    return (unsigned short)(r >> 16);
}

#define MFMA16(a,b,c) __builtin_amdgcn_mfma_f32_16x16x32_bf16((a),(b),(c),0,0,0)

// ---------------------------------------------------------------------------
// Fused: 3-layer MLP (bf16 MFMA) + bf16 Q/K store + chunk K^T·V sums.
// 64-row tiles -> 416 blocks (Q:0-63 | m0:64-127 | m1:128-223 | m2:224-351 |
// m3:352-415). W staged per-layer in LDS (coalesced — the R5-proven path).
// LDS ~40.5 KB -> 3 blocks/CU capacity, ~2 co-resident: TLP + half the chain.
__global__ __launch_bounds__(256) void k_fused(
    const float* __restrict__ x0, const float* __restrict__ x1,
    const float* __restrict__ x2, const float* __restrict__ x3,
    const float* __restrict__ wq_w, const float* __restrict__ wq_b,
    const float* __restrict__ wk_w, const float* __restrict__ wk_b,
    float* __restrict__ ws)
{
    __shared__ unsigned short H0[64*72];   // act ping [row][col]
    __shared__ unsigned short H1[64*72];   // act pong [row][col]
    __shared__ unsigned short Wt[64*72];   // W^T layer [c][d]
    __shared__ unsigned short KT[64*72];   // K^T [d][j]
    __shared__ unsigned short VT[32*72];   // V^T [e][j]

    const int tid = threadIdx.x;
    const int bid = blockIdx.x;

    int task, rb;
    if (bid < 64)       { task = 0; rb = bid; }
    else if (bid < 128) { task = 1; rb = bid - 64; }
    else if (bid < 224) { task = 2; rb = bid - 128; }
    else if (bid < 352) { task = 3; rb = bid - 224; }
    else                { task = 4; rb = bid - 352; }

    const float* Xs[4] = {x0, x1, x2, x3};
    const int rowoff[4] = {0, 4096, 10240, 18432};
    const int spoff[4]  = {0, 65, 162, 291};

    const float* X; const float* W; const float* Bv; int mm = -1;
    if (task == 0) { X = x0; W = wq_w; Bv = wq_b; }
    else {
        mm = task - 1;
        X = Xs[mm]; W = wk_w + mm*3*64*64; Bv = wk_b + mm*3*64;
    }

    const int row0 = rb * 64;
    // stage X tile -> H0 bf16 [row][col]
    {
        const float4* X4 = (const float4*)(X + (size_t)row0*64);
        #pragma unroll
        for (int k = 0; k < 4; ++k) {
            int idx = k*256 + tid;            // 0..1023 float4s
            float4 v = X4[idx];
            int rr = idx >> 4, c4 = (idx & 15) * 4;
            ushort4 h;
            h.x = f2bf(v.x); h.y = f2bf(v.y); h.z = f2bf(v.z); h.w = f2bf(v.w);
            *(ushort4*)&H0[rr*72 + c4] = h;
        }
    }
    // dense timestamps (fp32, never through bf16)
    if (task > 0 && tid < 64)
        ws[TD_OFF + rowoff[mm] + row0 + tid] = X[(size_t)(row0 + tid)*64 + 63];

    const int w    = tid >> 6;      // wave id = n-tile
    const int lane = tid & 63;
    const int lm   = lane & 15;
    const int q    = lane >> 4;
    const int col  = w*16 + lm;

    #pragma unroll 1
    for (int l = 0; l < 3; ++l) {
        __syncthreads();            // prior-layer Wt/H reads done (or X stage)
        // stage W^T for this layer (coalesced)
        {
            const float4* W4 = (const float4*)(W + l*4096);
            #pragma unroll
            for (int k = 0; k < 4; ++k) {
                int idx = k*256 + tid;        // 0..1023
                float4 v = W4[idx];
                int d = idx >> 4, c4 = (idx & 15) * 4;
                Wt[(c4+0)*72 + d] = f2bf(v.x);
                Wt[(c4+1)*72 + d] = f2bf(v.y);
                Wt[(c4+2)*72 + d] = f2bf(v.z);
                Wt[(c4+3)*72 + d] = f2bf(v.w);
            }
        }
        __syncthreads();

        const unsigned short* Hin  = (l & 1) ? H1 : H0;
        unsigned short*       Hout = (l & 1) ? H0 : H1;
        float bias = Bv[l*64 + col];
        short8 b0 = *(const short8*)&Wt[col*72 + q*8];
        short8 b1 = *(const short8*)&Wt[col*72 + 32 + q*8];
        #pragma unroll
        for (int mt = 0; mt < 4; ++mt) {
            floatx4 acc = {bias, bias, bias, bias};
            short8 a0 = *(const short8*)&Hin[(mt*16+lm)*72 + q*8];
            short8 a1 = *(const short8*)&Hin[(mt*16+lm)*72 + 32 + q*8];
            acc = MFMA16(a0, b0, acc);
            acc = MFMA16(a1, b1, acc);
            int r0 = mt*16 + q*4;
            #pragma unroll
            for (int r = 0; r < 4; ++r) {
                float f = acc[r];
                if (l < 2) f = fmaxf(f, 0.0f);
                unsigned short hb = f2bf(f);
                Hout[(r0+r)*72 + col] = hb;
                if (l == 2 && task > 0) KT[col*72 + r0 + r] = hb;  // K^T [d][j]
            }
        }
    }
    __syncthreads();

    // coalesced bf16 global store of final activations (in H1)
    {
        unsigned short* dst = (task == 0)
            ? (unsigned short*)(ws + QB_OFF)
            : (unsigned short*)(ws + KB_OFF) + (size_t)rowoff[mm]*64;
        #pragma unroll
        for (int k = 0; k < 4; ++k) {
            int idx = k*256 + tid;            // 0..1023 ushort4s
            int rr = idx >> 4, c4 = (idx & 15) * 4;
            *(ushort4*)&dst[(size_t)(row0 + rr)*64 + c4] = *(ushort4*)&H1[rr*72 + c4];
        }
    }
    if (task == 0) return;

    // stage V^T (X cols 0..31) + zero module slot 0
    {
        #pragma unroll
        for (int k = 0; k < 2; ++k) {
            int idx = k*256 + tid;            // 0..511 float4s
            int j = idx >> 3, e4 = (idx & 7) * 4;
            float4 v = *(const float4*)&X[(size_t)(row0 + j)*64 + e4];
            VT[(e4+0)*72 + j] = f2bf(v.x);
            VT[(e4+1)*72 + j] = f2bf(v.y);
            VT[(e4+2)*72 + j] = f2bf(v.z);
            VT[(e4+3)*72 + j] = f2bf(v.w);
        }
    }
    float* spbase = ws + SP_OFF + (size_t)spoff[mm]*2048;
    if (rb == 0)
        for (int idx = tid; idx < 2048; idx += 256) spbase[idx] = 0.0f;
    __syncthreads();

    // chunk sum S[d][e] = sum_j K[j][d] V[j][e]; wave w owns d-tile w
    {
        float* slot = spbase + (size_t)(rb + 1) * 2048;
        #pragma unroll
        for (int nt = 0; nt < 2; ++nt) {
            floatx4 acc = {0.f, 0.f, 0.f, 0.f};
            #pragma unroll
            for (int ks = 0; ks < 2; ++ks) {
                short8 aa = *(const short8*)&KT[col*72 + ks*32 + q*8];
                short8 bb = *(const short8*)&VT[(nt*16+lm)*72 + ks*32 + q*8];
                acc = MFMA16(aa, bb, acc);
            }
            #pragma unroll
            for (int r = 0; r < 4; ++r)
                slot[(w*16 + q*4 + r)*32 + nt*16 + lm] = acc[r];
        }
    }
}

// ---------------------------------------------------------------------------
// 42 blocks x 256: 0..31 in-place fp32 scan over SP slots (8192 chains);
// 32..33 tile c-bounds table; 34..41 zero d_out (replaces memset dispatch).
__global__ __launch_bounds__(256) void k_prefix(float* __restrict__ ws,
                                                float* __restrict__ out)
{
    const int nslots[4] = {65, 97, 129, 65};
    const int spoff[4]  = {0, 65, 162, 291};
    const int Tm[4]     = {4096, 6144, 8192, 4096};
    const int rowoff[4] = {0, 4096, 10240, 18432};
    const int bid = blockIdx.x;
    const int tid = threadIdx.x;

    if (bid < 32) {
        int chain = bid*256 + tid;              // 8192 chains
        int m = chain >> 11, entry = chain & 2047;
        float* p = ws + SP_OFF + (size_t)spoff[m]*2048 + entry;
        const int n = nslots[m];
        float s = 0.0f;
        #pragma unroll 8
        for (int k = 0; k < n; ++k) {
            float v = p[(size_t)k*2048];
            s += v;
            p[(size_t)k*2048] = s;
        }
    } else if (bid < 34) {
        const float* td = ws + TD_OFF;
        int* ctab = (int*)(ws + C_OFF);
        int g = (bid - 32)*256 + tid;           // 0..511
        int m = g >> 7, tile = (g >> 1) & 63, bound = g & 1;
        float t = td[tile*64 + (bound ? 63 : 0)];
        const float* t2 = td + rowoff[m];
        int lo = 0, hi = Tm[m];
        while (lo < hi) {
            int mid = (lo + hi) >> 1;
            if (t2[mid] <= t) lo = mid + 1; else hi = mid;
        }
        ctab[g] = lo;
    } else {
        float4 z = make_float4(0.f, 0.f, 0.f, 0.f);
        #pragma unroll
        for (int k = 0; k < 16; ++k)            // 8 blocks x 256 x 16 = 32768
            ((float4*)out)[(bid - 34)*4096 + k*256 + tid] = z;
    }
}

// ---------------------------------------------------------------------------
// Tiled MFMA query kernel, chunk-slot split (R8-verified): 512 blocks =
// (module m, 64-query tile, slot in {0,1}).
__global__ __launch_bounds__(256) void k_query(
    const float* __restrict__ x0, const float* __restrict__ x1,
    const float* __restrict__ x2, const float* __restrict__ x3,
    float* __restrict__ ws, float* __restrict__ out)
{
    __shared__ unsigned short qs[64*72];   // Q  [i][d]
    __shared__ unsigned short kc[64*72];   // K  [j][d]  (chunk)
    __shared__ unsigned short vt[32*72];   // V^T [e][j] (chunk)
    __shared__ unsigned short st[32*72];   // S^T [e][d] (slot 0 only)
    __shared__ unsigned short ps[64*72];   // masked P [i][j] (chunk)
    __shared__ float tq[64];               // t1 tile (fp32!)
    __shared__ float tcs[64];              // t2 chunk (fp32!)

    const int tid  = threadIdx.x;
    const int m    = blockIdx.x & 3;
    const int tile = (blockIdx.x >> 2) & 63;
    const int slot = blockIdx.x >> 8;      // 0 or 1
    const int i0   = tile * 64;

    const float* Xs[4] = {x0, x1, x2, x3};
    const int rowoff[4] = {0, 4096, 10240, 18432};
    const int spoff[4]  = {0, 65, 162, 291};
    const float* X = Xs[m];

    const int* ctab = (const int*)(ws + C_OFF);
    const int c_lo = ctab[m*128 + tile*2 + 0];
    const int c_hi = ctab[m*128 + tile*2 + 1];
    const int B0   = c_lo >> 6;
    const int Bhi  = (c_hi + 63) >> 6;

    if (slot == 1 && B0 + 1 >= Bhi) return;

    const unsigned short* Qg = (const unsigned short*)(ws + QB_OFF);
    const unsigned short* Kg = (const unsigned short*)(ws + KB_OFF) + (size_t)rowoff[m]*64;
    const float* td = ws + TD_OFF;
    const float* sp = ws + SP_OFF + (size_t)(spoff[m] + B0)*2048;

    #pragma unroll
    for (int k = 0; k < 4; ++k) {
        int idx = k*256 + tid;
        int rr = idx >> 4, c4 = (idx & 15) * 4;
        *(ushort4*)&qs[rr*72 + c4] = *(const ushort4*)&Qg[(size_t)(i0 + rr)*64 + c4];
    }
    if (slot == 0) {
        #pragma unroll
        for (int k = 0; k < 8; ++k) {
            int idx = k*256 + tid;
            int d = idx >> 5, e = idx & 31;
            st[e*72 + d] = f2bf(sp[idx]);
        }
    }
    if (tid < 64) tq[tid] = td[i0 + tid];
    __syncthreads();

    const int w    = tid >> 6;
    const int lane = tid & 63;
    const int lm   = lane & 15;
    const int q    = lane >> 4;

    float t1v[16];
    #pragma unroll
    for (int mt = 0; mt < 4; ++mt)
        #pragma unroll
        for (int r = 0; r < 4; ++r)
            t1v[mt*4 + r] = tq[mt*16 + q*4 + r];

    short8 qa[4][2];
    #pragma unroll
    for (int mt = 0; mt < 4; ++mt) {
        qa[mt][0] = *(const short8*)&qs[(mt*16+lm)*72 + q*8];
        qa[mt][1] = *(const short8*)&qs[(mt*16+lm)*72 + 32 + q*8];
    }

    floatx4 accO[2];
    accO[0] = (floatx4){0.f, 0.f, 0.f, 0.f};
    accO[1] = (floatx4){0.f, 0.f, 0.f, 0.f};

    if (slot == 0) {
        #pragma unroll
        for (int nt = 0; nt < 2; ++nt) {
            #pragma unroll
            for (int ks = 0; ks < 2; ++ks) {
                short8 b = *(const short8*)&st[(nt*16+lm)*72 + ks*32 + q*8];
                accO[nt] = MFMA16(qa[w][ks], b, accO[nt]);
            }
        }
    }

    #pragma unroll 1
    for (int B = B0 + slot; B < Bhi; B += 2) {
        __syncthreads();
        #pragma unroll
        for (int k = 0; k < 4; ++k) {
            int idx = k*256 + tid;
            int j = idx >> 4, c4 = (idx & 15) * 4;
            *(ushort4*)&kc[j*72 + c4] = *(const ushort4*)&Kg[(size_t)(B*64 + j)*64 + c4];
        }
        #pragma unroll
        for (int k = 0; k < 2; ++k) {
            int idx = k*256 + tid;
            int j = idx >> 3, e4 = (idx & 7) * 4;
            float4 v = *(const float4*)&X[(size_t)(B*64 + j)*64 + e4];
            vt[(e4+0)*72 + j] = f2bf(v.x);
            vt[(e4+1)*72 + j] = f2bf(v.y);
            vt[(e4+2)*72 + j] = f2bf(v.z);
            vt[(e4+3)*72 + j] = f2bf(v.w);
        }
        if (tid < 64) tcs[tid] = td[rowoff[m] + B*64 + tid];
        __syncthreads();

        {
            short8 bk0 = *(const short8*)&kc[(w*16+lm)*72 + q*8];
            short8 bk1 = *(const short8*)&kc[(w*16+lm)*72 + 32 + q*8];
            float t2j = tcs[w*16 + lm];
            #pragma unroll
            for (int mt = 0; mt < 4; ++mt) {
                floatx4 f = {0.f, 0.f, 0.f, 0.f};
                f = MFMA16(qa[mt][0], bk0, f);
                f = MFMA16(qa[mt][1], bk1, f);
                #pragma unroll
                for (int r = 0; r < 4; ++r) {
                    float p = (t2j <= t1v[mt*4 + r]) ? f[r] : 0.0f;
                    ps[(mt*16 + q*4 + r)*72 + w*16 + lm] = f2bf(p);
                }
            }
        }
        __syncthreads();

        {
            short8 pa0 = *(const short8*)&ps[(w*16+lm)*72 + q*8];
            short8 pa1 = *(const short8*)&ps[(w*16+lm)*72 + 32 + q*8];
            #pragma unroll
            for (int nt = 0; nt < 2; ++nt) {
                short8 bv0 = *(const short8*)&vt[(nt*16+lm)*72 + q*8];
                short8 bv1 = *(const short8*)&vt[(nt*16+lm)*72 + 32 + q*8];
                accO[nt] = MFMA16(pa0, bv0, accO[nt]);
                accO[nt] = MFMA16(pa1, bv1, accO[nt]);
            }
        }
    }

    #pragma unroll
    for (int nt = 0; nt < 2; ++nt)
        #pragma unroll
        for (int r = 0; r < 4; ++r) {
            int i = w*16 + q*4 + r;
            int e = nt*16 + lm;
            atomicAdd(&out[(size_t)(i0 + i)*32 + e], accO[nt][r]);
        }
}

extern "C" void kernel_launch(void* const* d_in, const int* in_sizes, int n_in,
                              void* d_out, int out_size, void* d_ws, size_t ws_size,
                              hipStream_t stream) {
    const float* x0   = (const float*)d_in[0];
    const float* x1   = (const float*)d_in[1];
    const float* x2   = (const float*)d_in[2];
    const float* x3   = (const float*)d_in[3];
    const float* wq_w = (const float*)d_in[4];
    const float* wq_b = (const float*)d_in[5];
    const float* wk_w = (const float*)d_in[6];
    const float* wk_b = (const float*)d_in[7];
    float* ws  = (float*)d_ws;
    float* out = (float*)d_out;

    hipLaunchKernelGGL(k_fused,  dim3(416), dim3(256), 0, stream,
                       x0, x1, x2, x3, wq_w, wq_b, wk_w, wk_b, ws);
    hipLaunchKernelGGL(k_prefix, dim3(42),  dim3(256), 0, stream, ws, out);
    hipLaunchKernelGGL(k_query,  dim3(512), dim3(256), 0, stream,
                       x0, x1, x2, x3, ws, out);
}

// Round 10
// 106.531 us; speedup vs baseline: 2.3664x; 1.0011x over previous
//
#include <hip/hip_runtime.h>

// Problem constants
//   m1:(1,1,4096,64) m2:(1,1,6144,64) m3:(1,1,8192,64) m4:(1,1,4096,64) fp32
//   WQ_w:(3,64,64) WQ_b:(3,64) WK_w:(4,3,64,64) WK_b:(4,3,64)
//   out:(1,4096,32) fp32
//
// Workspace layout (float units):
//   Qb   bf16 [4096][64]                 @ 0          (131072 fl)
//   Kb   bf16 per module [T_m][64]       @ 131072     (720896 fl)
//   SP   fp32 356 slots x 2048 (d*32+e)  @ 851968     (729088 fl)
//   TD   fp32 dense t2 per module        @ 1581056    (22528 fl)
//   CTAB int[4][64][2] tile c-bounds     @ 1603584    (512)

#define QB_OFF   0
#define KB_OFF   131072
#define SP_OFF   851968
#define TD_OFF   1581056
#define C_OFF    1603584

typedef __attribute__((ext_vector_type(8))) short short8;    // bf16 frag (4 VGPR)
typedef __attribute__((ext_vector_type(4))) float floatx4;   // MFMA C/D

__device__ __forceinline__ unsigned short f2bf(float f) {
    union { float f; unsigned u; } v; v.f = f;
    unsigned r = v.u + 0x7fff + ((v.u >> 16) & 1);   // RNE
    return (unsigned short)(r >> 16);
}

#define MFMA16(a,b,c) __builtin_amdgcn_mfma_f32_16x16x32_bf16((a),(b),(c),0,0,0)

// ---------------------------------------------------------------------------
// Fused: 3-layer MLP (bf16 MFMA) + bf16 Q/K store + chunk K^T·V sums.
// 64-row tiles -> 416 blocks. ALL 3 W layers pre-staged with the X tile in
// one up-front global batch (W is 48KB, L2-hot) -> exactly one global-latency
// round trip per block and one barrier per layer. LDS 59.9 KB (2 blocks/CU
// capacity >= the 1.6 needed at 416 blocks).
__global__ __launch_bounds__(256) void k_fused(
    const float* __restrict__ x0, const float* __restrict__ x1,
    const float* __restrict__ x2, const float* __restrict__ x3,
    const float* __restrict__ wq_w, const float* __restrict__ wq_b,
    const float* __restrict__ wk_w, const float* __restrict__ wk_b,
    float* __restrict__ ws)
{
    __shared__ unsigned short H0[64*72];      // act ping [row][col]
    __shared__ unsigned short H1[64*72];      // act pong [row][col]
    __shared__ unsigned short Wt[3][64*72];   // W^T all layers [c][d]
    __shared__ unsigned short KT[64*72];      // K^T [d][j]
    __shared__ unsigned short VT[32*72];      // V^T [e][j]

    const int tid = threadIdx.x;
    const int bid = blockIdx.x;

    int task, rb;
    if (bid < 64)       { task = 0; rb = bid; }
    else if (bid < 128) { task = 1; rb = bid - 64; }
    else if (bid < 224) { task = 2; rb = bid - 128; }
    else if (bid < 352) { task = 3; rb = bid - 224; }
    else                { task = 4; rb = bid - 352; }

    const float* Xs[4] = {x0, x1, x2, x3};
    const int rowoff[4] = {0, 4096, 10240, 18432};
    const int spoff[4]  = {0, 65, 162, 291};

    const float* X; const float* W; const float* Bv; int mm = -1;
    if (task == 0) { X = x0; W = wq_w; Bv = wq_b; }
    else {
        mm = task - 1;
        X = Xs[mm]; W = wk_w + mm*3*64*64; Bv = wk_b + mm*3*64;
    }

    const int row0 = rb * 64;

    // ---- one up-front global batch: X tile + all 3 W layers ----
    {
        const float4* X4 = (const float4*)(X + (size_t)row0*64);
        #pragma unroll
        for (int k = 0; k < 4; ++k) {
            int idx = k*256 + tid;            // 0..1023 float4s
            float4 v = X4[idx];
            int rr = idx >> 4, c4 = (idx & 15) * 4;
            ushort4 h;
            h.x = f2bf(v.x); h.y = f2bf(v.y); h.z = f2bf(v.z); h.w = f2bf(v.w);
            *(ushort4*)&H0[rr*72 + c4] = h;
        }
        const float4* W4 = (const float4*)W;
        #pragma unroll
        for (int k = 0; k < 12; ++k) {
            int idx = k*256 + tid;            // 0..3071 float4s over 3 layers
            float4 v = W4[idx];
            int l = idx >> 10, rest = idx & 1023;
            int d = rest >> 4, c4 = (rest & 15) * 4;
            Wt[l][(c4+0)*72 + d] = f2bf(v.x);
            Wt[l][(c4+1)*72 + d] = f2bf(v.y);
            Wt[l][(c4+2)*72 + d] = f2bf(v.z);
            Wt[l][(c4+3)*72 + d] = f2bf(v.w);
        }
    }
    // dense timestamps (fp32, never through bf16)
    if (task > 0 && tid < 64)
        ws[TD_OFF + rowoff[mm] + row0 + tid] = X[(size_t)(row0 + tid)*64 + 63];
    __syncthreads();

    const int w    = tid >> 6;      // wave id = n-tile
    const int lane = tid & 63;
    const int lm   = lane & 15;
    const int q    = lane >> 4;
    const int col  = w*16 + lm;

    // ---- 3 MFMA layers, ONE barrier each (ping-pong) ----
    #pragma unroll 1
    for (int l = 0; l < 3; ++l) {
        const unsigned short* Hin  = (l & 1) ? H1 : H0;
        unsigned short*       Hout = (l & 1) ? H0 : H1;
        float bias = Bv[l*64 + col];
        short8 b0 = *(const short8*)&Wt[l][col*72 + q*8];
        short8 b1 = *(const short8*)&Wt[l][col*72 + 32 + q*8];
        #pragma unroll
        for (int mt = 0; mt < 4; ++mt) {
            floatx4 acc = {bias, bias, bias, bias};
            short8 a0 = *(const short8*)&Hin[(mt*16+lm)*72 + q*8];
            short8 a1 = *(const short8*)&Hin[(mt*16+lm)*72 + 32 + q*8];
            acc = MFMA16(a0, b0, acc);
            acc = MFMA16(a1, b1, acc);
            int r0 = mt*16 + q*4;
            #pragma unroll
            for (int r = 0; r < 4; ++r) {
                float f = acc[r];
                if (l < 2) f = fmaxf(f, 0.0f);
                unsigned short hb = f2bf(f);
                Hout[(r0+r)*72 + col] = hb;
                if (l == 2 && task > 0) KT[col*72 + r0 + r] = hb;  // K^T [d][j]
            }
        }
        __syncthreads();
    }

    // coalesced bf16 global store of final activations (in H1)
    {
        unsigned short* dst = (task == 0)
            ? (unsigned short*)(ws + QB_OFF)
            : (unsigned short*)(ws + KB_OFF) + (size_t)rowoff[mm]*64;
        #pragma unroll
        for (int k = 0; k < 4; ++k) {
            int idx = k*256 + tid;            // 0..1023 ushort4s
            int rr = idx >> 4, c4 = (idx & 15) * 4;
            *(ushort4*)&dst[(size_t)(row0 + rr)*64 + c4] = *(ushort4*)&H1[rr*72 + c4];
        }
    }
    if (task == 0) return;

    // stage V^T (X cols 0..31) + zero module slot 0
    {
        #pragma unroll
        for (int k = 0; k < 2; ++k) {
            int idx = k*256 + tid;            // 0..511 float4s
            int j = idx >> 3, e4 = (idx & 7) * 4;
            float4 v = *(const float4*)&X[(size_t)(row0 + j)*64 + e4];
            VT[(e4+0)*72 + j] = f2bf(v.x);
            VT[(e4+1)*72 + j] = f2bf(v.y);
            VT[(e4+2)*72 + j] = f2bf(v.z);
            VT[(e4+3)*72 + j] = f2bf(v.w);
        }
    }
    float* spbase = ws + SP_OFF + (size_t)spoff[mm]*2048;
    if (rb == 0)
        for (int idx = tid; idx < 2048; idx += 256) spbase[idx] = 0.0f;
    __syncthreads();

    // chunk sum S[d][e] = sum_j K[j][d] V[j][e]; wave w owns d-tile w
    {
        float* slot = spbase + (size_t)(rb + 1) * 2048;
        #pragma unroll
        for (int nt = 0; nt < 2; ++nt) {
            floatx4 acc = {0.f, 0.f, 0.f, 0.f};
            #pragma unroll
            for (int ks = 0; ks < 2; ++ks) {
                short8 aa = *(const short8*)&KT[col*72 + ks*32 + q*8];
                short8 bb = *(const short8*)&VT[(nt*16+lm)*72 + ks*32 + q*8];
                acc = MFMA16(aa, bb, acc);
            }
            #pragma unroll
            for (int r = 0; r < 4; ++r)
                slot[(w*16 + q*4 + r)*32 + nt*16 + lm] = acc[r];
        }
    }
}

// ---------------------------------------------------------------------------
// 42 blocks x 256: 0..31 in-place fp32 scan over SP slots (8192 chains);
// 32..33 tile c-bounds table; 34..41 zero d_out (replaces memset dispatch).
__global__ __launch_bounds__(256) void k_prefix(float* __restrict__ ws,
                                                float* __restrict__ out)
{
    const int nslots[4] = {65, 97, 129, 65};
    const int spoff[4]  = {0, 65, 162, 291};
    const int Tm[4]     = {4096, 6144, 8192, 4096};
    const int rowoff[4] = {0, 4096, 10240, 18432};
    const int bid = blockIdx.x;
    const int tid = threadIdx.x;

    if (bid < 32) {
        int chain = bid*256 + tid;              // 8192 chains
        int m = chain >> 11, entry = chain & 2047;
        float* p = ws + SP_OFF + (size_t)spoff[m]*2048 + entry;
        const int n = nslots[m];
        float s = 0.0f;
        #pragma unroll 8
        for (int k = 0; k < n; ++k) {
            float v = p[(size_t)k*2048];
            s += v;
            p[(size_t)k*2048] = s;
        }
    } else if (bid < 34) {
        const float* td = ws + TD_OFF;
        int* ctab = (int*)(ws + C_OFF);
        int g = (bid - 32)*256 + tid;           // 0..511
        int m = g >> 7, tile = (g >> 1) & 63, bound = g & 1;
        float t = td[tile*64 + (bound ? 63 : 0)];
        const float* t2 = td + rowoff[m];
        int lo = 0, hi = Tm[m];
        while (lo < hi) {
            int mid = (lo + hi) >> 1;
            if (t2[mid] <= t) lo = mid + 1; else hi = mid;
        }
        ctab[g] = lo;
    } else {
        float4 z = make_float4(0.f, 0.f, 0.f, 0.f);
        #pragma unroll
        for (int k = 0; k < 16; ++k)            // 8 blocks x 256 x 16 = 32768
            ((float4*)out)[(bid - 34)*4096 + k*256 + tid] = z;
    }
}

// ---------------------------------------------------------------------------
// Tiled MFMA query kernel, chunk-slot split (R8-verified): 512 blocks =
// (module m, 64-query tile, slot in {0,1}).
__global__ __launch_bounds__(256) void k_query(
    const float* __restrict__ x0, const float* __restrict__ x1,
    const float* __restrict__ x2, const float* __restrict__ x3,
    float* __restrict__ ws, float* __restrict__ out)
{
    __shared__ unsigned short qs[64*72];   // Q  [i][d]
    __shared__ unsigned short kc[64*72];   // K  [j][d]  (chunk)
    __shared__ unsigned short vt[32*72];   // V^T [e][j] (chunk)
    __shared__ unsigned short st[32*72];   // S^T [e][d] (slot 0 only)
    __shared__ unsigned short ps[64*72];   // masked P [i][j] (chunk)
    __shared__ float tq[64];               // t1 tile (fp32!)
    __shared__ float tcs[64];              // t2 chunk (fp32!)

    const int tid  = threadIdx.x;
    const int m    = blockIdx.x & 3;
    const int tile = (blockIdx.x >> 2) & 63;
    const int slot = blockIdx.x >> 8;      // 0 or 1
    const int i0   = tile * 64;

    const float* Xs[4] = {x0, x1, x2, x3};
    const int rowoff[4] = {0, 4096, 10240, 18432};
    const int spoff[4]  = {0, 65, 162, 291};
    const float* X = Xs[m];

    const int* ctab = (const int*)(ws + C_OFF);
    const int c_lo = ctab[m*128 + tile*2 + 0];
    const int c_hi = ctab[m*128 + tile*2 + 1];
    const int B0   = c_lo >> 6;
    const int Bhi  = (c_hi + 63) >> 6;

    if (slot == 1 && B0 + 1 >= Bhi) return;

    const unsigned short* Qg = (const unsigned short*)(ws + QB_OFF);
    const unsigned short* Kg = (const unsigned short*)(ws + KB_OFF) + (size_t)rowoff[m]*64;
    const float* td = ws + TD_OFF;
    const float* sp = ws + SP_OFF + (size_t)(spoff[m] + B0)*2048;

    #pragma unroll
    for (int k = 0; k < 4; ++k) {
        int idx = k*256 + tid;
        int rr = idx >> 4, c4 = (idx & 15) * 4;
        *(ushort4*)&qs[rr*72 + c4] = *(const ushort4*)&Qg[(size_t)(i0 + rr)*64 + c4];
    }
    if (slot == 0) {
        #pragma unroll
        for (int k = 0; k < 8; ++k) {
            int idx = k*256 + tid;
            int d = idx >> 5, e = idx & 31;
            st[e*72 + d] = f2bf(sp[idx]);
        }
    }
    if (tid < 64) tq[tid] = td[i0 + tid];
    __syncthreads();

    const int w    = tid >> 6;
    const int lane = tid & 63;
    const int lm   = lane & 15;
    const int q    = lane >> 4;

    float t1v[16];
    #pragma unroll
    for (int mt = 0; mt < 4; ++mt)
        #pragma unroll
        for (int r = 0; r < 4; ++r)
            t1v[mt*4 + r] = tq[mt*16 + q*4 + r];

    short8 qa[4][2];
    #pragma unroll
    for (int mt = 0; mt < 4; ++mt) {
        qa[mt][0] = *(const short8*)&qs[(mt*16+lm)*72 + q*8];
        qa[mt][1] = *(const short8*)&qs[(mt*16+lm)*72 + 32 + q*8];
    }

    floatx4 accO[2];
    accO[0] = (floatx4){0.f, 0.f, 0.f, 0.f};
    accO[1] = (floatx4){0.f, 0.f, 0.f, 0.f};

    if (slot == 0) {
        #pragma unroll
        for (int nt = 0; nt < 2; ++nt) {
            #pragma unroll
            for (int ks = 0; ks < 2; ++ks) {
                short8 b = *(const short8*)&st[(nt*16+lm)*72 + ks*32 + q*8];
                accO[nt] = MFMA16(qa[w][ks], b, accO[nt]);
            }
        }
    }

    #pragma unroll 1
    for (int B = B0 + slot; B < Bhi; B += 2) {
        __syncthreads();
        #pragma unroll
        for (int k = 0; k < 4; ++k) {
            int idx = k*256 + tid;
            int j = idx >> 4, c4 = (idx & 15) * 4;
            *(ushort4*)&kc[j*72 + c4] = *(const ushort4*)&Kg[(size_t)(B*64 + j)*64 + c4];
        }
        #pragma unroll
        for (int k = 0; k < 2; ++k) {
            int idx = k*256 + tid;
            int j = idx >> 3, e4 = (idx & 7) * 4;
            float4 v = *(const float4*)&X[(size_t)(B*64 + j)*64 + e4];
            vt[(e4+0)*72 + j] = f2bf(v.x);
            vt[(e4+1)*72 + j] = f2bf(v.y);
            vt[(e4+2)*72 + j] = f2bf(v.z);
            vt[(e4+3)*72 + j] = f2bf(v.w);
        }
        if (tid < 64) tcs[tid] = td[rowoff[m] + B*64 + tid];
        __syncthreads();

        {
            short8 bk0 = *(const short8*)&kc[(w*16+lm)*72 + q*8];
            short8 bk1 = *(const short8*)&kc[(w*16+lm)*72 + 32 + q*8];
            float t2j = tcs[w*16 + lm];
            #pragma unroll
            for (int mt = 0; mt < 4; ++mt) {
                floatx4 f = {0.f, 0.f, 0.f, 0.f};
                f = MFMA16(qa[mt][0], bk0, f);
                f = MFMA16(qa[mt][1], bk1, f);
                #pragma unroll
                for (int r = 0; r < 4; ++r) {
                    float p = (t2j <= t1v[mt*4 + r]) ? f[r] : 0.0f;
                    ps[(mt*16 + q*4 + r)*72 + w*16 + lm] = f2bf(p);
                }
            }
        }
        __syncthreads();

        {
            short8 pa0 = *(const short8*)&ps[(w*16+lm)*72 + q*8];
            short8 pa1 = *(const short8*)&ps[(w*16+lm)*72 + 32 + q*8];
            #pragma unroll
            for (int nt = 0; nt < 2; ++nt) {
                short8 bv0 = *(const short8*)&vt[(nt*16+lm)*72 + q*8];
                short8 bv1 = *(const short8*)&vt[(nt*16+lm)*72 + 32 + q*8];
                accO[nt] = MFMA16(pa0, bv0, accO[nt]);
                accO[nt] = MFMA16(pa1, bv1, accO[nt]);
            }
        }
    }

    #pragma unroll
    for (int nt = 0; nt < 2; ++nt)
        #pragma unroll
        for (int r = 0; r < 4; ++r) {
            int i = w*16 + q*4 + r;
            int e = nt*16 + lm;
            atomicAdd(&out[(size_t)(i0 + i)*32 + e], accO[nt][r]);
        }
}

extern "C" void kernel_launch(void* const* d_in, const int* in_sizes, int n_in,
                              void* d_out, int out_size, void* d_ws, size_t ws_size,
                              hipStream_t stream) {
    const float* x0   = (const float*)d_in[0];
    const float* x1   = (const float*)d_in[1];
    const float* x2   = (const float*)d_in[2];
    const float* x3   = (const float*)d_in[3];
    const float* wq_w = (const float*)d_in[4];
    const float* wq_b = (const float*)d_in[5];
    const float* wk_w = (const float*)d_in[6];
    const float* wk_b = (const float*)d_in[7];
    float* ws  = (float*)d_ws;
    float* out = (float*)d_out;

    hipLaunchKernelGGL(k_fused,  dim3(416), dim3(256), 0, stream,
                       x0, x1, x2, x3, wq_w, wq_b, wk_w, wk_b, ws);
    hipLaunchKernelGGL(k_prefix, dim3(42),  dim3(256), 0, stream, ws, out);
    hipLaunchKernelGGL(k_query,  dim3(512), dim3(256), 0, stream,
                       x0, x1, x2, x3, ws, out);
}